// Round 13
// baseline (175.444 us; speedup 1.0000x reference)
//
#include <hip/hip_runtime.h>
#include <hip/hip_bf16.h>

typedef __bf16 bf16;
typedef __bf16 bf16x8 __attribute__((ext_vector_type(8)));
typedef __bf16 bf16x4 __attribute__((ext_vector_type(4)));
typedef float f32x4 __attribute__((ext_vector_type(4)));
typedef float f32x16 __attribute__((ext_vector_type(16)));
typedef unsigned int u32x2 __attribute__((ext_vector_type(2)));

#define EMBED 1024
#define NH 16
#define HD 64
#define BATCH 2
#define SEQ 2048
#define MTOK 4096
#define LOG2E 1.4426950408889634f

static __device__ __forceinline__ float fast_exp2(float x) {
#if __has_builtin(__builtin_amdgcn_exp2f)
  return __builtin_amdgcn_exp2f(x);
#else
  float r;
  asm("v_exp_f32 %0, %1" : "=v"(r) : "v"(x));
  return r;
#endif
}

static __device__ __forceinline__ f32x4 mfma16(bf16x8 a, bf16x8 b, f32x4 c) {
  return __builtin_amdgcn_mfma_f32_16x16x32_bf16(a, b, c, 0, 0, 0);
}
static __device__ __forceinline__ f32x16 mfma32(bf16x8 a, bf16x8 b, f32x16 c) {
  return __builtin_amdgcn_mfma_f32_32x32x16_bf16(a, b, c, 0, 0, 0);
}

static __device__ __forceinline__ void gld_lds16(const bf16* g, bf16* l) {
  __builtin_amdgcn_global_load_lds(
      (const __attribute__((address_space(1))) void*)g,
      (__attribute__((address_space(3))) void*)l, 16, 0, 0);
}

// ---------------- fused prep ----------------
// blocks [0,2048): x->bf16 ; [2048,2304): k_w^T ; [2304,2560): v_w^T ;
// [2560,2816): out_w^T ; [2816,3072): weff ; [3072,3088): beff
__global__ __launch_bounds__(256) void prep_kernel(
    const float* __restrict__ x, const float* __restrict__ qw,
    const float* __restrict__ qb, const float* __restrict__ kw,
    const float* __restrict__ vw, const float* __restrict__ ow,
    const float* __restrict__ ent, const float* __restrict__ phase,
    bf16* __restrict__ xb, bf16* __restrict__ wtall, bf16* __restrict__ wot,
    float* __restrict__ beff) {
  __shared__ float t0[64][65];
  __shared__ float t1[64][65];
  const int bb = blockIdx.x;
  const int tid = threadIdx.x;

  if (bb < 2048) {  // cvt x
    const int n4 = MTOK * EMBED / 4;
    int i = bb * 256 + tid;
    for (; i < n4; i += 2048 * 256) {
      f32x4 v = ((const f32x4*)x)[i];
      bf16x4 o;
      o[0] = (bf16)v[0]; o[1] = (bf16)v[1]; o[2] = (bf16)v[2]; o[3] = (bf16)v[3];
      ((bf16x4*)xb)[i] = o;
    }
    return;
  }
  if (bb < 2816) {  // transposes
    const int idx = (bb - 2048) & 255;
    const float* W = (bb < 2304) ? kw : (bb < 2560) ? vw : ow;
    bf16* Wt = (bb < 2304) ? (wtall + 1024 * 1024)
             : (bb < 2560) ? (wtall + 2 * 1024 * 1024) : wot;
    const int bc = (idx & 15) * 64;
    const int br = (idx >> 4) * 64;
#pragma unroll
    for (int j = 0; j < 16; j++) {
      int id2 = j * 256 + tid;
      int r = id2 >> 6, c = id2 & 63;
      t0[r][c] = W[(size_t)(br + r) * EMBED + bc + c];
    }
    __syncthreads();
#pragma unroll
    for (int j = 0; j < 16; j++) {
      int id2 = j * 256 + tid;
      int r = id2 >> 6, c = id2 & 63;
      Wt[(size_t)(bc + r) * EMBED + br + c] = (bf16)t0[c][r];
    }
    return;
  }
  if (bb < 3072) {  // weff: W_q_eff^T = (q_w @ blockdiag(E')*log2e)^T
    const int idx = bb - 2816;
    const int h = idx >> 4;
    const int ibase = (idx & 15) * 64;
#pragma unroll
    for (int j = 0; j < 16; j++) {
      int id2 = j * 256 + tid;
      int i = id2 >> 6, d = id2 & 63;
      t0[i][d] = qw[(size_t)(ibase + i) * EMBED + h * HD + d];
    }
#pragma unroll
    for (int j = 0; j < 16; j++) {
      int id2 = j * 256 + tid;
      int d = id2 >> 6, e = id2 & 63;
      float v = ent[((size_t)h * HD + d) * HD + e];
      if (d == e) { float cp = cosf(phase[h * HD + d]); v += cp * cp * 0.125f; }
      t1[d][e] = v * LOG2E;
    }
    __syncthreads();
    const int i = tid & 63;
    const int e0 = (tid >> 6) * 16;
    float s[16];
#pragma unroll
    for (int ee = 0; ee < 16; ee++) s[ee] = 0.f;
    for (int d = 0; d < 64; d++) {
      float qv = t0[i][d];
#pragma unroll
      for (int ee = 0; ee < 16; ee++) s[ee] += qv * t1[d][e0 + ee];
    }
#pragma unroll
    for (int ee = 0; ee < 16; ee++)
      wtall[(size_t)(h * HD + e0 + ee) * EMBED + ibase + i] = (bf16)s[ee];
    return;
  }
  // beff
  const int h = bb - 3072;
  if (tid < 64) {
    const int e = tid;
    float s = 0.f;
    for (int d = 0; d < 64; d++) {
      float v = ent[((size_t)h * HD + d) * HD + e];
      if (d == e) { float cp = cosf(phase[h * HD + d]); v += cp * cp * 0.125f; }
      s += qb[h * HD + d] * v;
    }
    beff[h * HD + e] = s * LOG2E;
  }
}

// ---------------- QKV GEMM (single 768-block dispatch) ----------------
// A[4096][1024] bf16 x wtall[3072][1024]^T. seg = bn>>10: 0=Qeff, 1=K, 2=V.
// seg 0/1: SWAPPED mfma(bfv,af) -> lane r15 = token row, regs = 4 consecutive
//   N-cols -> bf16x4 stores. seg 2: unswapped -> transposed V store [b,h,d][s]
//   with regs = 4 consecutive tokens. seg is block-uniform -> branch is free.
__global__ __launch_bounds__(256) void gemm_qkv_kernel(
    const bf16* __restrict__ A, const bf16* __restrict__ Bt,
    const float* __restrict__ bias_q, const float* __restrict__ bias_k,
    const float* __restrict__ bias_v,
    bf16* __restrict__ Qp, bf16* __restrict__ Kp, bf16* __restrict__ Vt) {
  const int tid = threadIdx.x;
  const int lane = tid & 63, w = tid >> 6;
  const int g = lane >> 4, r15 = lane & 15;
  const int wr = w >> 1, wc = w & 1;

  // bijective XCD swizzle: 768 = 8 * 96
  const int flat = blockIdx.x;
  const int swz = (flat & 7) * 96 + (flat >> 3);
  const int bm = (swz & 31) * 128;
  const int bn = (swz >> 5) * 128;
  const int seg = bn >> 10;

  __shared__ bf16 sA[128 * 32];
  __shared__ bf16 sB[128 * 32];

  f32x4 acc[4][4];
#pragma unroll
  for (int m = 0; m < 4; m++)
#pragma unroll
    for (int n = 0; n < 4; n++) acc[m][n] = (f32x4){0.f, 0.f, 0.f, 0.f};

  const int srow = tid >> 2;
  const int scol = (tid & 3) << 3;
  const bf16* aptr = A + (size_t)(bm + srow) * EMBED + scol;
  const bf16* bptr = Bt + (size_t)(bn + srow) * EMBED + scol;
  bf16* la = sA + tid * 8;
  bf16* lb = sB + tid * 8;

  for (int k0 = 0; k0 < EMBED; k0 += 32) {
    __syncthreads();
    gld_lds16(aptr + k0, la);
    gld_lds16(aptr + k0 + 64 * EMBED, la + 64 * 32);
    gld_lds16(bptr + k0, lb);
    gld_lds16(bptr + k0 + 64 * EMBED, lb + 64 * 32);
    __syncthreads();
    bf16x8 af[4], bfv[4];
#pragma unroll
    for (int m = 0; m < 4; m++)
      af[m] = *(const bf16x8*)&sA[(wr * 64 + m * 16 + r15) * 32 + g * 8];
#pragma unroll
    for (int n = 0; n < 4; n++)
      bfv[n] = *(const bf16x8*)&sB[(wc * 64 + n * 16 + r15) * 32 + g * 8];
    if (seg == 2) {
#pragma unroll
      for (int m = 0; m < 4; m++)
#pragma unroll
        for (int n = 0; n < 4; n++) acc[m][n] = mfma16(af[m], bfv[n], acc[m][n]);
    } else {
#pragma unroll
      for (int m = 0; m < 4; m++)
#pragma unroll
        for (int n = 0; n < 4; n++) acc[m][n] = mfma16(bfv[n], af[m], acc[m][n]);
    }
  }

  if (seg == 2) {
    // unswapped: V -> [b,h,d][s], regs = 4 consecutive tokens s
    const int clb = (bn & 1023) + wc * 64;
    const int orow0 = bm + wr * 64;
#pragma unroll
    for (int n = 0; n < 4; n++) {
      const int cl = clb + n * 16 + r15;
      const float bias = bias_v[cl];
      const int hh = cl >> 6, d = cl & 63;
#pragma unroll
      for (int m = 0; m < 4; m++) {
        const int row0 = orow0 + m * 16 + g * 4;
        const int b = row0 >> 11, s = row0 & 2047;
        bf16x4 pk;
#pragma unroll
        for (int r = 0; r < 4; r++) pk[r] = (bf16)(acc[m][n][r] + bias);
        *(bf16x4*)(Vt + ((size_t)((b * NH + hh) * HD + d)) * SEQ + s) = pk;
      }
    }
  } else {
    // swapped: token row = bm + wr*64 + m*16 + r15; cols cl4..cl4+3
    const float* bias = seg ? bias_k : bias_q;
    bf16* dst = seg ? Kp : Qp;
    const int clb = (bn & 1023) + wc * 64;
#pragma unroll
    for (int n = 0; n < 4; n++) {
      const int cl4 = clb + n * 16 + g * 4;
      const f32x4 b4 = *(const f32x4*)&bias[cl4];
#pragma unroll
      for (int m = 0; m < 4; m++) {
        const int tr = bm + wr * 64 + m * 16 + r15;
        bf16x4 pk;
#pragma unroll
        for (int r = 0; r < 4; r++) pk[r] = (bf16)(acc[m][n][r] + b4[r]);
        *(bf16x4*)(dst + (size_t)tr * EMBED + cl4) = pk;
      }
    }
  }
}

// ---------------- out-proj GEMM (swapped, fp32 f32x4 stores) --------------
__global__ __launch_bounds__(256) void gemm_out_kernel(
    const bf16* __restrict__ A, const bf16* __restrict__ Bt,
    const float* __restrict__ bias_o, float* __restrict__ FO) {
  const int tid = threadIdx.x;
  const int lane = tid & 63, w = tid >> 6;
  const int g = lane >> 4, r15 = lane & 15;
  const int wr = w >> 1, wc = w & 1;

  // bijective XCD swizzle: 256 = 8 * 32
  const int flat = blockIdx.x;
  const int swz = (flat & 7) * 32 + (flat >> 3);
  const int bm = (swz & 31) * 128;
  const int bn = (swz >> 5) * 128;

  __shared__ bf16 sA[128 * 32];
  __shared__ bf16 sB[128 * 32];

  f32x4 acc[4][4];
#pragma unroll
  for (int m = 0; m < 4; m++)
#pragma unroll
    for (int n = 0; n < 4; n++) acc[m][n] = (f32x4){0.f, 0.f, 0.f, 0.f};

  const int srow = tid >> 2;
  const int scol = (tid & 3) << 3;
  const bf16* aptr = A + (size_t)(bm + srow) * EMBED + scol;
  const bf16* bptr = Bt + (size_t)(bn + srow) * EMBED + scol;
  bf16* la = sA + tid * 8;
  bf16* lb = sB + tid * 8;

  for (int k0 = 0; k0 < EMBED; k0 += 32) {
    __syncthreads();
    gld_lds16(aptr + k0, la);
    gld_lds16(aptr + k0 + 64 * EMBED, la + 64 * 32);
    gld_lds16(bptr + k0, lb);
    gld_lds16(bptr + k0 + 64 * EMBED, lb + 64 * 32);
    __syncthreads();
    bf16x8 af[4], bfv[4];
#pragma unroll
    for (int m = 0; m < 4; m++)
      af[m] = *(const bf16x8*)&sA[(wr * 64 + m * 16 + r15) * 32 + g * 8];
#pragma unroll
    for (int n = 0; n < 4; n++)
      bfv[n] = *(const bf16x8*)&sB[(wc * 64 + n * 16 + r15) * 32 + g * 8];
#pragma unroll
    for (int m = 0; m < 4; m++)
#pragma unroll
      for (int n = 0; n < 4; n++) acc[m][n] = mfma16(bfv[n], af[m], acc[m][n]);
  }

  const int clb = bn + wc * 64;
#pragma unroll
  for (int n = 0; n < 4; n++) {
    const int cl4 = clb + n * 16 + g * 4;
    const f32x4 b4 = *(const f32x4*)&bias_o[cl4];
#pragma unroll
    for (int m = 0; m < 4; m++) {
      const int tr = bm + wr * 64 + m * 16 + r15;
      *(f32x4*)(FO + (size_t)tr * EMBED + cl4) = acc[m][n] + b4;
    }
  }
}

// ---------------- flash attention (32x32 MFMA, in-block KV-split) --------
// 512 blocks (XCD-swizzled) x 512 thr = 8 waves. Waves 0-3: kv [0,1024),
// waves 4-7: kv [1024,2048); each wave owns 32 q-rows with its own (m,l,O).
// Per half: KVBLK=64 K/V double-buffered LDS (XOR-swizzled), counted
// vmcnt(4). In-register P via permlane32_swap. Merge halves through LDS.
__global__ __launch_bounds__(512, 4) void flash_attn_kernel(
    const bf16* __restrict__ Qp, const bf16* __restrict__ Kp,
    const bf16* __restrict__ Vt, bf16* __restrict__ Op) {
  const int tid = threadIdx.x, lane = tid & 63, w = tid >> 6;
  const int q31 = lane & 31, hi = lane >> 5;
  const int half = w >> 2, wq = w & 3;
  // bijective XCD swizzle: 512 blocks = 8 xcd * 64; chunk = 4 bh * 16 qt
  const int flat = blockIdx.x;
  const int c = (flat & 7) * 64 + (flat >> 3);
  const int bh = c >> 4, qt = c & 15;
  const int b = bh >> 4, h = bh & 15;

  __shared__ char smem[65536];
  bf16* sKb = (bf16*)smem;             // [half*2+buf][4096] : 64 kv x 64 d
  bf16* sVb = (bf16*)(smem + 32768);   // [half*2+buf][4096] : 64 d  x 64 s

  const int g256 = tid & 255;          // within-half staging id
  const int strow = g256 >> 3;         // 0..31
  const int stcb = (g256 & 7) << 4;

  const char* kgbase = (const char*)(Kp + ((size_t)b * SEQ) * EMBED + h * HD);
  const char* vgbase = (const char*)(Vt + (size_t)bh * HD * SEQ);

  auto stage = [&](int buf, int kv0) {
    bf16* kd = sKb + (size_t)(half * 2 + buf) * 4096 + g256 * 8;
    bf16* vd = sVb + (size_t)(half * 2 + buf) * 4096 + g256 * 8;
#pragma unroll
    for (int i = 0; i < 2; i++) {
      const int row = i * 32 + strow;
      const int sb = stcb ^ ((row & 7) << 4);
      gld_lds16((const bf16*)(kgbase + (size_t)(kv0 + row) * (EMBED * 2) + sb),
                kd + i * 2048);
      gld_lds16((const bf16*)(vgbase + (size_t)row * (SEQ * 2) + (size_t)kv0 * 2 + sb),
                vd + i * 2048);
    }
  };

  const int kvbase = half * 1024;
  stage(0, kvbase);

  // Q B-operand frags: lane q31 = q-col, k-slice hi*8 within each 16-depth
  const int qbase = qt * 128 + wq * 32;
  const int qrow = qbase + q31;
  const bf16* qptr = Qp + ((size_t)(b * SEQ + qrow)) * EMBED + h * HD;
  bf16x8 aq[4];
#pragma unroll
  for (int ds = 0; ds < 4; ds++)
    aq[ds] = *(const bf16x8*)(qptr + ds * 16 + hi * 8);

  const int sz = (q31 & 7) << 4;
  int cofs[4];  // 128B-row chunk offsets: i*32 + hi*16, swizzled
#pragma unroll
  for (int i = 0; i < 4; i++) cofs[i] = ((i * 32 + hi * 16) ^ sz);

  f32x16 o0, o1;
#pragma unroll
  for (int i = 0; i < 16; i++) { o0[i] = 0.f; o1[i] = 0.f; }
  float mrow = -3.0e38f, lrow = 0.f;

  union B4 { bf16x4 v; unsigned int u[2]; };

  for (int it = 0; it < 16; ++it) {
    const int cur = it & 1;
    if (it + 1 < 16) {
      stage(cur ^ 1, kvbase + (it + 1) * 64);
      asm volatile("s_waitcnt vmcnt(4)" ::: "memory");
    } else {
      asm volatile("s_waitcnt vmcnt(0)" ::: "memory");
    }
    __builtin_amdgcn_s_barrier();

    const char* kc = (const char*)(sKb + (size_t)(half * 2 + cur) * 4096) + q31 * 128;
    const char* vc = (const char*)(sVb + (size_t)(half * 2 + cur) * 4096) + q31 * 128;

    // ---- QK^T: A = K (rows kv), B = Q -> S[kv][q] ----
    f32x16 s0, s1;
#pragma unroll
    for (int i = 0; i < 16; i++) { s0[i] = 0.f; s1[i] = 0.f; }
    __builtin_amdgcn_s_setprio(1);
#pragma unroll
    for (int ds = 0; ds < 4; ds++) {
      bf16x8 bk0 = *(const bf16x8*)(kc + cofs[ds]);
      bf16x8 bk1 = *(const bf16x8*)(kc + 4096 + cofs[ds]);
      s0 = mfma32(bk0, aq[ds], s0);
      s1 = mfma32(bk1, aq[ds], s1);
    }
    __builtin_amdgcn_s_setprio(0);

    // ---- per-lane softmax over the 32 held scores (exp2 domain) ----
    float mt = s0[0];
#pragma unroll
    for (int i = 1; i < 16; i++) mt = fmaxf(mt, s0[i]);
#pragma unroll
    for (int i = 0; i < 16; i++) mt = fmaxf(mt, s1[i]);
    {
      u32x2 sm = __builtin_amdgcn_permlane32_swap(__float_as_uint(mt),
                                                  __float_as_uint(mt), false, false);
      mt = fmaxf(__uint_as_float(sm.x), __uint_as_float(sm.y));
    }
    if (__any(mt > mrow + 8.f)) {
      const float mn = fmaxf(mrow, mt);
      const float al = fast_exp2(mrow - mn);
      mrow = mn;
      lrow *= al;
      o0 *= al;
      o1 *= al;
    }

    // P = exp2(S - mrow): pack into 8 quads (bf16x4 = 2 dwords each)
    B4 qd[8];
    float lsum = 0.f;
#pragma unroll
    for (int j = 0; j < 4; j++)
#pragma unroll
      for (int r = 0; r < 4; r++) {
        float pv = fast_exp2(s0[4 * j + r] - mrow);
        lsum += pv;
        qd[j].v[r] = (bf16)pv;
      }
#pragma unroll
    for (int j = 0; j < 4; j++)
#pragma unroll
      for (int r = 0; r < 4; r++) {
        float pv = fast_exp2(s1[4 * j + r] - mrow);
        lsum += pv;
        qd[4 + j].v[r] = (bf16)pv;
      }
    {
      u32x2 ss = __builtin_amdgcn_permlane32_swap(__float_as_uint(lsum),
                                                  __float_as_uint(lsum), false, false);
      lrow += __uint_as_float(ss.x) + __uint_as_float(ss.y);  // own + partner
    }

    // assemble PV B-fragments: frag[kt] covers kv = kt*16 .. +15
    bf16x8 pfrag[4];
#pragma unroll
    for (int kt = 0; kt < 4; kt++) {
      u32x2 p0 = __builtin_amdgcn_permlane32_swap(qd[2 * kt].u[0],
                                                  qd[2 * kt + 1].u[0], false, false);
      u32x2 p1 = __builtin_amdgcn_permlane32_swap(qd[2 * kt].u[1],
                                                  qd[2 * kt + 1].u[1], false, false);
      union { unsigned int u[4]; bf16x8 v; } f;
      f.u[0] = p0.x; f.u[1] = p1.x; f.u[2] = p0.y; f.u[3] = p1.y;
      pfrag[kt] = f.v;
    }

    // ---- PV: A = V^T (rows d), B = P -> O[d][q] ----
    __builtin_amdgcn_s_setprio(1);
#pragma unroll
    for (int kt = 0; kt < 4; kt++) {
      bf16x8 av0 = *(const bf16x8*)(vc + cofs[kt]);
      bf16x8 av1 = *(const bf16x8*)(vc + 4096 + cofs[kt]);
      o0 = mfma32(av0, pfrag[kt], o0);
      o1 = mfma32(av1, pfrag[kt], o1);
    }
    __builtin_amdgcn_s_setprio(0);
    __builtin_amdgcn_s_barrier();
  }

  // ---- merge halves through reused LDS ----
  float* shO = (float*)smem;             // [4][64][33]
  float* shML = (float*)(smem + 33792);  // [4][64][2]
  if (half == 1) {
    float* o = shO + (size_t)(wq * 64 + lane) * 33;
#pragma unroll
    for (int i = 0; i < 16; i++) { o[i] = o0[i]; o[16 + i] = o1[i]; }
    shML[(wq * 64 + lane) * 2] = mrow;
    shML[(wq * 64 + lane) * 2 + 1] = lrow;
  }
  __syncthreads();
  if (half == 0) {
    const float* o = shO + (size_t)(wq * 64 + lane) * 33;
    const float mB = shML[(wq * 64 + lane) * 2];
    const float lB = shML[(wq * 64 + lane) * 2 + 1];
    const float M = fmaxf(mrow, mB);
    const float wA = fast_exp2(mrow - M), wB = fast_exp2(mB - M);
    const float inv = 1.f / (lrow * wA + lB * wB);
    const float fA = wA * inv, fB = wB * inv;

    // O[d][q]: lane q31 owns q-col; d = 8*j + 4*hi + r (o0), +32 (o1)
    bf16* obase = Op + ((size_t)(b * SEQ + qrow)) * EMBED + h * HD;
#pragma unroll
    for (int j = 0; j < 4; j++) {
      bf16x4 st;
#pragma unroll
      for (int r = 0; r < 4; r++)
        st[r] = (bf16)(o0[4 * j + r] * fA + o[4 * j + r] * fB);
      *(bf16x4*)(obase + 8 * j + 4 * hi) = st;
    }
#pragma unroll
    for (int j = 0; j < 4; j++) {
      bf16x4 st;
#pragma unroll
      for (int r = 0; r < 4; r++)
        st[r] = (bf16)(o1[4 * j + r] * fA + o[16 + 4 * j + r] * fB);
      *(bf16x4*)(obase + 32 + 8 * j + 4 * hi) = st;
    }
  }
}

// ---------------- launch ----------------
extern "C" void kernel_launch(void* const* d_in, const int* in_sizes, int n_in,
                              void* d_out, int out_size, void* d_ws, size_t ws_size,
                              hipStream_t stream) {
  const float* x     = (const float*)d_in[0];
  const float* q_w   = (const float*)d_in[1];
  const float* q_b   = (const float*)d_in[2];
  const float* k_w   = (const float*)d_in[3];
  const float* k_b   = (const float*)d_in[4];
  const float* v_w   = (const float*)d_in[5];
  const float* v_b   = (const float*)d_in[6];
  const float* phase = (const float*)d_in[7];
  const float* ent   = (const float*)d_in[8];
  const float* out_w = (const float*)d_in[9];
  const float* out_b = (const float*)d_in[10];
  float* out = (float*)d_out;

  char* ws = (char*)d_ws;
  bf16* xb    = (bf16*)(ws + 0);          // 8388608 B, [B,S,E] bf16; reused as attn out
  bf16* wtall = (bf16*)(ws + 8388608);    // 6291456 B, [3072][1024] bf16 (Qeff|K|V)
  bf16* wot   = (bf16*)(ws + 14680064);   // 2097152 B, out_w^T bf16
  float* beff = (float*)(ws + 16777216);  // 4096 B
  bf16* Qp    = (bf16*)(ws + 16781312);   // 8388608 B
  bf16* Kp    = (bf16*)(ws + 25169920);   // 8388608 B
  bf16* Vt    = (bf16*)(ws + 33558528);   // 8388608 B, [b,h,d,s]
  (void)in_sizes; (void)n_in; (void)out_size; (void)ws_size;

  prep_kernel<<<3088, 256, 0, stream>>>(x, q_w, q_b, k_w, v_w, out_w, ent, phase,
                                        xb, wtall, wot, beff);

  gemm_qkv_kernel<<<768, 256, 0, stream>>>(
      xb, wtall, beff, k_b, v_b, Qp, Kp, Vt);

  flash_attn_kernel<<<512, 512, 0, stream>>>(Qp, Kp, Vt, xb);

  gemm_out_kernel<<<256, 256, 0, stream>>>(xb, wot, out_b, out);
}

// Round 14
// 167.258 us; speedup vs baseline: 1.0489x; 1.0489x over previous
//
#include <hip/hip_runtime.h>
#include <hip/hip_bf16.h>

typedef __bf16 bf16;
typedef __bf16 bf16x8 __attribute__((ext_vector_type(8)));
typedef __bf16 bf16x4 __attribute__((ext_vector_type(4)));
typedef float f32x4 __attribute__((ext_vector_type(4)));
typedef float f32x16 __attribute__((ext_vector_type(16)));
typedef unsigned int u32x2 __attribute__((ext_vector_type(2)));

#define EMBED 1024
#define NH 16
#define HD 64
#define BATCH 2
#define SEQ 2048
#define MTOK 4096
#define LOG2E 1.4426950408889634f

static __device__ __forceinline__ float fast_exp2(float x) {
#if __has_builtin(__builtin_amdgcn_exp2f)
  return __builtin_amdgcn_exp2f(x);
#else
  float r;
  asm("v_exp_f32 %0, %1" : "=v"(r) : "v"(x));
  return r;
#endif
}

static __device__ __forceinline__ f32x4 mfma16(bf16x8 a, bf16x8 b, f32x4 c) {
  return __builtin_amdgcn_mfma_f32_16x16x32_bf16(a, b, c, 0, 0, 0);
}
static __device__ __forceinline__ f32x16 mfma32(bf16x8 a, bf16x8 b, f32x16 c) {
  return __builtin_amdgcn_mfma_f32_32x32x16_bf16(a, b, c, 0, 0, 0);
}

static __device__ __forceinline__ void gld_lds16(const bf16* g, bf16* l) {
  __builtin_amdgcn_global_load_lds(
      (const __attribute__((address_space(1))) void*)g,
      (__attribute__((address_space(3))) void*)l, 16, 0, 0);
}

// ---------------- fused prep ----------------
// blocks [0,2048): x->bf16 ; [2048,2304): k_w^T ; [2304,2560): v_w^T ;
// [2560,2816): out_w^T ; [2816,3072): weff ; [3072,3088): beff
__global__ __launch_bounds__(256) void prep_kernel(
    const float* __restrict__ x, const float* __restrict__ qw,
    const float* __restrict__ qb, const float* __restrict__ kw,
    const float* __restrict__ vw, const float* __restrict__ ow,
    const float* __restrict__ ent, const float* __restrict__ phase,
    bf16* __restrict__ xb, bf16* __restrict__ wtall, bf16* __restrict__ wot,
    float* __restrict__ beff) {
  __shared__ float t0[64][65];
  __shared__ float t1[64][65];
  const int bb = blockIdx.x;
  const int tid = threadIdx.x;

  if (bb < 2048) {  // cvt x
    const int n4 = MTOK * EMBED / 4;
    int i = bb * 256 + tid;
    for (; i < n4; i += 2048 * 256) {
      f32x4 v = ((const f32x4*)x)[i];
      bf16x4 o;
      o[0] = (bf16)v[0]; o[1] = (bf16)v[1]; o[2] = (bf16)v[2]; o[3] = (bf16)v[3];
      ((bf16x4*)xb)[i] = o;
    }
    return;
  }
  if (bb < 2816) {  // transposes
    const int idx = (bb - 2048) & 255;
    const float* W = (bb < 2304) ? kw : (bb < 2560) ? vw : ow;
    bf16* Wt = (bb < 2304) ? (wtall + 1024 * 1024)
             : (bb < 2560) ? (wtall + 2 * 1024 * 1024) : wot;
    const int bc = (idx & 15) * 64;
    const int br = (idx >> 4) * 64;
#pragma unroll
    for (int j = 0; j < 16; j++) {
      int id2 = j * 256 + tid;
      int r = id2 >> 6, c = id2 & 63;
      t0[r][c] = W[(size_t)(br + r) * EMBED + bc + c];
    }
    __syncthreads();
#pragma unroll
    for (int j = 0; j < 16; j++) {
      int id2 = j * 256 + tid;
      int r = id2 >> 6, c = id2 & 63;
      Wt[(size_t)(bc + r) * EMBED + br + c] = (bf16)t0[c][r];
    }
    return;
  }
  if (bb < 3072) {  // weff: W_q_eff^T = (q_w @ blockdiag(E')*log2e)^T
    const int idx = bb - 2816;
    const int h = idx >> 4;
    const int ibase = (idx & 15) * 64;
#pragma unroll
    for (int j = 0; j < 16; j++) {
      int id2 = j * 256 + tid;
      int i = id2 >> 6, d = id2 & 63;
      t0[i][d] = qw[(size_t)(ibase + i) * EMBED + h * HD + d];
    }
#pragma unroll
    for (int j = 0; j < 16; j++) {
      int id2 = j * 256 + tid;
      int d = id2 >> 6, e = id2 & 63;
      float v = ent[((size_t)h * HD + d) * HD + e];
      if (d == e) { float cp = cosf(phase[h * HD + d]); v += cp * cp * 0.125f; }
      t1[d][e] = v * LOG2E;
    }
    __syncthreads();
    const int i = tid & 63;
    const int e0 = (tid >> 6) * 16;
    float s[16];
#pragma unroll
    for (int ee = 0; ee < 16; ee++) s[ee] = 0.f;
    for (int d = 0; d < 64; d++) {
      float qv = t0[i][d];
#pragma unroll
      for (int ee = 0; ee < 16; ee++) s[ee] += qv * t1[d][e0 + ee];
    }
#pragma unroll
    for (int ee = 0; ee < 16; ee++)
      wtall[(size_t)(h * HD + e0 + ee) * EMBED + ibase + i] = (bf16)s[ee];
    return;
  }
  // beff
  const int h = bb - 3072;
  if (tid < 64) {
    const int e = tid;
    float s = 0.f;
    for (int d = 0; d < 64; d++) {
      float v = ent[((size_t)h * HD + d) * HD + e];
      if (d == e) { float cp = cosf(phase[h * HD + d]); v += cp * cp * 0.125f; }
      s += qb[h * HD + d] * v;
    }
    beff[h * HD + e] = s * LOG2E;
  }
}

// ---------------- QKV GEMM (single 768-block dispatch, NATURAL order) -----
// Natural mapping bm = flat&31, bn = flat>>5: each XCD holds only 4 bm
// panels (1 MB A resident in its L2) while B streams -- no L2 thrash.
// seg = bn>>10: 0=Qeff, 1=K (swapped mfma -> bf16x4 row-major stores);
// 2=V (unswapped -> transposed [b,h,d][s] bf16x4 stores).
__global__ __launch_bounds__(256) void gemm_qkv_kernel(
    const bf16* __restrict__ A, const bf16* __restrict__ Bt,
    const float* __restrict__ bias_q, const float* __restrict__ bias_k,
    const float* __restrict__ bias_v,
    bf16* __restrict__ Qp, bf16* __restrict__ Kp, bf16* __restrict__ Vt) {
  const int tid = threadIdx.x;
  const int lane = tid & 63, w = tid >> 6;
  const int g = lane >> 4, r15 = lane & 15;
  const int wr = w >> 1, wc = w & 1;

  const int flat = blockIdx.x;
  const int bm = (flat & 31) * 128;
  const int bn = (flat >> 5) * 128;
  const int seg = bn >> 10;

  __shared__ bf16 sA[128 * 32];
  __shared__ bf16 sB[128 * 32];

  f32x4 acc[4][4];
#pragma unroll
  for (int m = 0; m < 4; m++)
#pragma unroll
    for (int n = 0; n < 4; n++) acc[m][n] = (f32x4){0.f, 0.f, 0.f, 0.f};

  const int srow = tid >> 2;
  const int scol = (tid & 3) << 3;
  const bf16* aptr = A + (size_t)(bm + srow) * EMBED + scol;
  const bf16* bptr = Bt + (size_t)(bn + srow) * EMBED + scol;
  bf16* la = sA + tid * 8;
  bf16* lb = sB + tid * 8;

  for (int k0 = 0; k0 < EMBED; k0 += 32) {
    __syncthreads();
    gld_lds16(aptr + k0, la);
    gld_lds16(aptr + k0 + 64 * EMBED, la + 64 * 32);
    gld_lds16(bptr + k0, lb);
    gld_lds16(bptr + k0 + 64 * EMBED, lb + 64 * 32);
    __syncthreads();
    bf16x8 af[4], bfv[4];
#pragma unroll
    for (int m = 0; m < 4; m++)
      af[m] = *(const bf16x8*)&sA[(wr * 64 + m * 16 + r15) * 32 + g * 8];
#pragma unroll
    for (int n = 0; n < 4; n++)
      bfv[n] = *(const bf16x8*)&sB[(wc * 64 + n * 16 + r15) * 32 + g * 8];
    if (seg == 2) {
#pragma unroll
      for (int m = 0; m < 4; m++)
#pragma unroll
        for (int n = 0; n < 4; n++) acc[m][n] = mfma16(af[m], bfv[n], acc[m][n]);
    } else {
#pragma unroll
      for (int m = 0; m < 4; m++)
#pragma unroll
        for (int n = 0; n < 4; n++) acc[m][n] = mfma16(bfv[n], af[m], acc[m][n]);
    }
  }

  if (seg == 2) {
    // unswapped: V -> [b,h,d][s], regs = 4 consecutive tokens s
    const int clb = (bn & 1023) + wc * 64;
    const int orow0 = bm + wr * 64;
#pragma unroll
    for (int n = 0; n < 4; n++) {
      const int cl = clb + n * 16 + r15;
      const float bias = bias_v[cl];
      const int hh = cl >> 6, d = cl & 63;
#pragma unroll
      for (int m = 0; m < 4; m++) {
        const int row0 = orow0 + m * 16 + g * 4;
        const int b = row0 >> 11, s = row0 & 2047;
        bf16x4 pk;
#pragma unroll
        for (int r = 0; r < 4; r++) pk[r] = (bf16)(acc[m][n][r] + bias);
        *(bf16x4*)(Vt + ((size_t)((b * NH + hh) * HD + d)) * SEQ + s) = pk;
      }
    }
  } else {
    // swapped: token row = bm + wr*64 + m*16 + r15; cols cl4..cl4+3
    const float* bias = seg ? bias_k : bias_q;
    bf16* dst = seg ? Kp : Qp;
    const int clb = (bn & 1023) + wc * 64;
#pragma unroll
    for (int n = 0; n < 4; n++) {
      const int cl4 = clb + n * 16 + g * 4;
      const f32x4 b4 = *(const f32x4*)&bias[cl4];
#pragma unroll
      for (int m = 0; m < 4; m++) {
        const int tr = bm + wr * 64 + m * 16 + r15;
        bf16x4 pk;
#pragma unroll
        for (int r = 0; r < 4; r++) pk[r] = (bf16)(acc[m][n][r] + b4[r]);
        *(bf16x4*)(dst + (size_t)tr * EMBED + cl4) = pk;
      }
    }
  }
}

// ---------------- out-proj GEMM (swapped, fp32 f32x4 stores, natural) -----
__global__ __launch_bounds__(256) void gemm_out_kernel(
    const bf16* __restrict__ A, const bf16* __restrict__ Bt,
    const float* __restrict__ bias_o, float* __restrict__ FO) {
  const int tid = threadIdx.x;
  const int lane = tid & 63, w = tid >> 6;
  const int g = lane >> 4, r15 = lane & 15;
  const int wr = w >> 1, wc = w & 1;

  const int flat = blockIdx.x;
  const int bm = (flat & 31) * 128;
  const int bn = (flat >> 5) * 128;

  __shared__ bf16 sA[128 * 32];
  __shared__ bf16 sB[128 * 32];

  f32x4 acc[4][4];
#pragma unroll
  for (int m = 0; m < 4; m++)
#pragma unroll
    for (int n = 0; n < 4; n++) acc[m][n] = (f32x4){0.f, 0.f, 0.f, 0.f};

  const int srow = tid >> 2;
  const int scol = (tid & 3) << 3;
  const bf16* aptr = A + (size_t)(bm + srow) * EMBED + scol;
  const bf16* bptr = Bt + (size_t)(bn + srow) * EMBED + scol;
  bf16* la = sA + tid * 8;
  bf16* lb = sB + tid * 8;

  for (int k0 = 0; k0 < EMBED; k0 += 32) {
    __syncthreads();
    gld_lds16(aptr + k0, la);
    gld_lds16(aptr + k0 + 64 * EMBED, la + 64 * 32);
    gld_lds16(bptr + k0, lb);
    gld_lds16(bptr + k0 + 64 * EMBED, lb + 64 * 32);
    __syncthreads();
    bf16x8 af[4], bfv[4];
#pragma unroll
    for (int m = 0; m < 4; m++)
      af[m] = *(const bf16x8*)&sA[(wr * 64 + m * 16 + r15) * 32 + g * 8];
#pragma unroll
    for (int n = 0; n < 4; n++)
      bfv[n] = *(const bf16x8*)&sB[(wc * 64 + n * 16 + r15) * 32 + g * 8];
#pragma unroll
    for (int m = 0; m < 4; m++)
#pragma unroll
      for (int n = 0; n < 4; n++) acc[m][n] = mfma16(bfv[n], af[m], acc[m][n]);
  }

  const int clb = bn + wc * 64;
#pragma unroll
  for (int n = 0; n < 4; n++) {
    const int cl4 = clb + n * 16 + g * 4;
    const f32x4 b4 = *(const f32x4*)&bias_o[cl4];
#pragma unroll
    for (int m = 0; m < 4; m++) {
      const int tr = bm + wr * 64 + m * 16 + r15;
      *(f32x4*)(FO + (size_t)tr * EMBED + cl4) = acc[m][n] + b4;
    }
  }
}

// ---------------- flash attention (32x32 MFMA, in-block KV-split) --------
// 512 blocks (XCD-swizzled) x 512 thr = 8 waves. Waves 0-3: kv [0,1024),
// waves 4-7: kv [1024,2048); each wave owns 32 q-rows with its own (m,l,O).
// Per half: KVBLK=64 K/V double-buffered LDS (XOR-swizzled), counted
// vmcnt(4). In-register P via permlane32_swap. Merge halves through LDS.
__global__ __launch_bounds__(512, 4) void flash_attn_kernel(
    const bf16* __restrict__ Qp, const bf16* __restrict__ Kp,
    const bf16* __restrict__ Vt, bf16* __restrict__ Op) {
  const int tid = threadIdx.x, lane = tid & 63, w = tid >> 6;
  const int q31 = lane & 31, hi = lane >> 5;
  const int half = w >> 2, wq = w & 3;
  // bijective XCD swizzle: 512 blocks = 8 xcd * 64; chunk = 4 bh * 16 qt
  const int flat = blockIdx.x;
  const int c = (flat & 7) * 64 + (flat >> 3);
  const int bh = c >> 4, qt = c & 15;
  const int b = bh >> 4, h = bh & 15;

  __shared__ char smem[65536];
  bf16* sKb = (bf16*)smem;             // [half*2+buf][4096] : 64 kv x 64 d
  bf16* sVb = (bf16*)(smem + 32768);   // [half*2+buf][4096] : 64 d  x 64 s

  const int g256 = tid & 255;          // within-half staging id
  const int strow = g256 >> 3;         // 0..31
  const int stcb = (g256 & 7) << 4;

  const char* kgbase = (const char*)(Kp + ((size_t)b * SEQ) * EMBED + h * HD);
  const char* vgbase = (const char*)(Vt + (size_t)bh * HD * SEQ);

  auto stage = [&](int buf, int kv0) {
    bf16* kd = sKb + (size_t)(half * 2 + buf) * 4096 + g256 * 8;
    bf16* vd = sVb + (size_t)(half * 2 + buf) * 4096 + g256 * 8;
#pragma unroll
    for (int i = 0; i < 2; i++) {
      const int row = i * 32 + strow;
      const int sb = stcb ^ ((row & 7) << 4);
      gld_lds16((const bf16*)(kgbase + (size_t)(kv0 + row) * (EMBED * 2) + sb),
                kd + i * 2048);
      gld_lds16((const bf16*)(vgbase + (size_t)row * (SEQ * 2) + (size_t)kv0 * 2 + sb),
                vd + i * 2048);
    }
  };

  const int kvbase = half * 1024;
  stage(0, kvbase);

  // Q B-operand frags: lane q31 = q-col, k-slice hi*8 within each 16-depth
  const int qbase = qt * 128 + wq * 32;
  const int qrow = qbase + q31;
  const bf16* qptr = Qp + ((size_t)(b * SEQ + qrow)) * EMBED + h * HD;
  bf16x8 aq[4];
#pragma unroll
  for (int ds = 0; ds < 4; ds++)
    aq[ds] = *(const bf16x8*)(qptr + ds * 16 + hi * 8);

  const int sz = (q31 & 7) << 4;
  int cofs[4];  // 128B-row chunk offsets: i*32 + hi*16, swizzled
#pragma unroll
  for (int i = 0; i < 4; i++) cofs[i] = ((i * 32 + hi * 16) ^ sz);

  f32x16 o0, o1;
#pragma unroll
  for (int i = 0; i < 16; i++) { o0[i] = 0.f; o1[i] = 0.f; }
  float mrow = -3.0e38f, lrow = 0.f;

  union B4 { bf16x4 v; unsigned int u[2]; };

  for (int it = 0; it < 16; ++it) {
    const int cur = it & 1;
    if (it + 1 < 16) {
      stage(cur ^ 1, kvbase + (it + 1) * 64);
      asm volatile("s_waitcnt vmcnt(4)" ::: "memory");
    } else {
      asm volatile("s_waitcnt vmcnt(0)" ::: "memory");
    }
    __builtin_amdgcn_s_barrier();

    const char* kc = (const char*)(sKb + (size_t)(half * 2 + cur) * 4096) + q31 * 128;
    const char* vc = (const char*)(sVb + (size_t)(half * 2 + cur) * 4096) + q31 * 128;

    // ---- QK^T: A = K (rows kv), B = Q -> S[kv][q] ----
    f32x16 s0, s1;
#pragma unroll
    for (int i = 0; i < 16; i++) { s0[i] = 0.f; s1[i] = 0.f; }
    __builtin_amdgcn_s_setprio(1);
#pragma unroll
    for (int ds = 0; ds < 4; ds++) {
      bf16x8 bk0 = *(const bf16x8*)(kc + cofs[ds]);
      bf16x8 bk1 = *(const bf16x8*)(kc + 4096 + cofs[ds]);
      s0 = mfma32(bk0, aq[ds], s0);
      s1 = mfma32(bk1, aq[ds], s1);
    }
    __builtin_amdgcn_s_setprio(0);

    // ---- per-lane softmax over the 32 held scores (exp2 domain) ----
    float mt = s0[0];
#pragma unroll
    for (int i = 1; i < 16; i++) mt = fmaxf(mt, s0[i]);
#pragma unroll
    for (int i = 0; i < 16; i++) mt = fmaxf(mt, s1[i]);
    {
      u32x2 sm = __builtin_amdgcn_permlane32_swap(__float_as_uint(mt),
                                                  __float_as_uint(mt), false, false);
      mt = fmaxf(__uint_as_float(sm.x), __uint_as_float(sm.y));
    }
    if (__any(mt > mrow + 8.f)) {
      const float mn = fmaxf(mrow, mt);
      const float al = fast_exp2(mrow - mn);
      mrow = mn;
      lrow *= al;
      o0 *= al;
      o1 *= al;
    }

    // P = exp2(S - mrow): pack into 8 quads (bf16x4 = 2 dwords each)
    B4 qd[8];
    float lsum = 0.f;
#pragma unroll
    for (int j = 0; j < 4; j++)
#pragma unroll
      for (int r = 0; r < 4; r++) {
        float pv = fast_exp2(s0[4 * j + r] - mrow);
        lsum += pv;
        qd[j].v[r] = (bf16)pv;
      }
#pragma unroll
    for (int j = 0; j < 4; j++)
#pragma unroll
      for (int r = 0; r < 4; r++) {
        float pv = fast_exp2(s1[4 * j + r] - mrow);
        lsum += pv;
        qd[4 + j].v[r] = (bf16)pv;
      }
    {
      u32x2 ss = __builtin_amdgcn_permlane32_swap(__float_as_uint(lsum),
                                                  __float_as_uint(lsum), false, false);
      lrow += __uint_as_float(ss.x) + __uint_as_float(ss.y);  // own + partner
    }

    // assemble PV B-fragments: frag[kt] covers kv = kt*16 .. +15
    bf16x8 pfrag[4];
#pragma unroll
    for (int kt = 0; kt < 4; kt++) {
      u32x2 p0 = __builtin_amdgcn_permlane32_swap(qd[2 * kt].u[0],
                                                  qd[2 * kt + 1].u[0], false, false);
      u32x2 p1 = __builtin_amdgcn_permlane32_swap(qd[2 * kt].u[1],
                                                  qd[2 * kt + 1].u[1], false, false);
      union { unsigned int u[4]; bf16x8 v; } f;
      f.u[0] = p0.x; f.u[1] = p1.x; f.u[2] = p0.y; f.u[3] = p1.y;
      pfrag[kt] = f.v;
    }

    // ---- PV: A = V^T (rows d), B = P -> O[d][q] ----
    __builtin_amdgcn_s_setprio(1);
#pragma unroll
    for (int kt = 0; kt < 4; kt++) {
      bf16x8 av0 = *(const bf16x8*)(vc + cofs[kt]);
      bf16x8 av1 = *(const bf16x8*)(vc + 4096 + cofs[kt]);
      o0 = mfma32(av0, pfrag[kt], o0);
      o1 = mfma32(av1, pfrag[kt], o1);
    }
    __builtin_amdgcn_s_setprio(0);
    __builtin_amdgcn_s_barrier();
  }

  // ---- merge halves through reused LDS ----
  float* shO = (float*)smem;             // [4][64][33]
  float* shML = (float*)(smem + 33792);  // [4][64][2]
  if (half == 1) {
    float* o = shO + (size_t)(wq * 64 + lane) * 33;
#pragma unroll
    for (int i = 0; i < 16; i++) { o[i] = o0[i]; o[16 + i] = o1[i]; }
    shML[(wq * 64 + lane) * 2] = mrow;
    shML[(wq * 64 + lane) * 2 + 1] = lrow;
  }
  __syncthreads();
  if (half == 0) {
    const float* o = shO + (size_t)(wq * 64 + lane) * 33;
    const float mB = shML[(wq * 64 + lane) * 2];
    const float lB = shML[(wq * 64 + lane) * 2 + 1];
    const float M = fmaxf(mrow, mB);
    const float wA = fast_exp2(mrow - M), wB = fast_exp2(mB - M);
    const float inv = 1.f / (lrow * wA + lB * wB);
    const float fA = wA * inv, fB = wB * inv;

    // O[d][q]: lane q31 owns q-col; d = 8*j + 4*hi + r (o0), +32 (o1)
    bf16* obase = Op + ((size_t)(b * SEQ + qrow)) * EMBED + h * HD;
#pragma unroll
    for (int j = 0; j < 4; j++) {
      bf16x4 st;
#pragma unroll
      for (int r = 0; r < 4; r++)
        st[r] = (bf16)(o0[4 * j + r] * fA + o[4 * j + r] * fB);
      *(bf16x4*)(obase + 8 * j + 4 * hi) = st;
    }
#pragma unroll
    for (int j = 0; j < 4; j++) {
      bf16x4 st;
#pragma unroll
      for (int r = 0; r < 4; r++)
        st[r] = (bf16)(o1[4 * j + r] * fA + o[16 + 4 * j + r] * fB);
      *(bf16x4*)(obase + 32 + 8 * j + 4 * hi) = st;
    }
  }
}

// ---------------- launch ----------------
extern "C" void kernel_launch(void* const* d_in, const int* in_sizes, int n_in,
                              void* d_out, int out_size, void* d_ws, size_t ws_size,
                              hipStream_t stream) {
  const float* x     = (const float*)d_in[0];
  const float* q_w   = (const float*)d_in[1];
  const float* q_b   = (const float*)d_in[2];
  const float* k_w   = (const float*)d_in[3];
  const float* k_b   = (const float*)d_in[4];
  const float* v_w   = (const float*)d_in[5];
  const float* v_b   = (const float*)d_in[6];
  const float* phase = (const float*)d_in[7];
  const float* ent   = (const float*)d_in[8];
  const float* out_w = (const float*)d_in[9];
  const float* out_b = (const float*)d_in[10];
  float* out = (float*)d_out;

  char* ws = (char*)d_ws;
  bf16* xb    = (bf16*)(ws + 0);          // 8388608 B, [B,S,E] bf16; reused as attn out
  bf16* wtall = (bf16*)(ws + 8388608);    // 6291456 B, [3072][1024] bf16 (Qeff|K|V)
  bf16* wot   = (bf16*)(ws + 14680064);   // 2097152 B, out_w^T bf16
  float* beff = (float*)(ws + 16777216);  // 4096 B
  bf16* Qp    = (bf16*)(ws + 16781312);   // 8388608 B
  bf16* Kp    = (bf16*)(ws + 25169920);   // 8388608 B
  bf16* Vt    = (bf16*)(ws + 33558528);   // 8388608 B, [b,h,d,s]
  (void)in_sizes; (void)n_in; (void)out_size; (void)ws_size;

  prep_kernel<<<3088, 256, 0, stream>>>(x, q_w, q_b, k_w, v_w, out_w, ent, phase,
                                        xb, wtall, wot, beff);

  gemm_qkv_kernel<<<768, 256, 0, stream>>>(
      xb, wtall, beff, k_b, v_b, Qp, Kp, Vt);

  flash_attn_kernel<<<512, 512, 0, stream>>>(Qp, Kp, Vt, xb);

  gemm_out_kernel<<<256, 256, 0, stream>>>(xb, wot, out_b, out);
}

// Round 15
// 136.135 us; speedup vs baseline: 1.2888x; 1.2286x over previous
//
#include <hip/hip_runtime.h>
#include <hip/hip_bf16.h>

typedef __bf16 bf16;
typedef __bf16 bf16x8 __attribute__((ext_vector_type(8)));
typedef __bf16 bf16x4 __attribute__((ext_vector_type(4)));
typedef float f32x4 __attribute__((ext_vector_type(4)));
typedef float f32x16 __attribute__((ext_vector_type(16)));
typedef unsigned int u32x2 __attribute__((ext_vector_type(2)));

#define EMBED 1024
#define NH 16
#define HD 64
#define BATCH 2
#define SEQ 2048
#define MTOK 4096
#define LOG2E 1.4426950408889634f

static __device__ __forceinline__ float fast_exp2(float x) {
#if __has_builtin(__builtin_amdgcn_exp2f)
  return __builtin_amdgcn_exp2f(x);
#else
  float r;
  asm("v_exp_f32 %0, %1" : "=v"(r) : "v"(x));
  return r;
#endif
}

static __device__ __forceinline__ f32x4 mfma16(bf16x8 a, bf16x8 b, f32x4 c) {
  return __builtin_amdgcn_mfma_f32_16x16x32_bf16(a, b, c, 0, 0, 0);
}
static __device__ __forceinline__ f32x16 mfma32(bf16x8 a, bf16x8 b, f32x16 c) {
  return __builtin_amdgcn_mfma_f32_32x32x16_bf16(a, b, c, 0, 0, 0);
}

static __device__ __forceinline__ void gld_lds16(const bf16* g, bf16* l) {
  __builtin_amdgcn_global_load_lds(
      (const __attribute__((address_space(1))) void*)g,
      (__attribute__((address_space(3))) void*)l, 16, 0, 0);
}

// ---------------- fused prep ----------------
// blocks [0,2048): x->bf16 ; [2048,2304): k_w^T ; [2304,2560): v_w^T ;
// [2560,2816): out_w^T ; [2816,3072): weff ; [3072,3088): beff
__global__ __launch_bounds__(256) void prep_kernel(
    const float* __restrict__ x, const float* __restrict__ qw,
    const float* __restrict__ qb, const float* __restrict__ kw,
    const float* __restrict__ vw, const float* __restrict__ ow,
    const float* __restrict__ ent, const float* __restrict__ phase,
    bf16* __restrict__ xb, bf16* __restrict__ wtall, bf16* __restrict__ wot,
    float* __restrict__ beff) {
  __shared__ float t0[64][65];
  __shared__ float t1[64][65];
  const int bb = blockIdx.x;
  const int tid = threadIdx.x;

  if (bb < 2048) {  // cvt x
    const int n4 = MTOK * EMBED / 4;
    int i = bb * 256 + tid;
    for (; i < n4; i += 2048 * 256) {
      f32x4 v = ((const f32x4*)x)[i];
      bf16x4 o;
      o[0] = (bf16)v[0]; o[1] = (bf16)v[1]; o[2] = (bf16)v[2]; o[3] = (bf16)v[3];
      ((bf16x4*)xb)[i] = o;
    }
    return;
  }
  if (bb < 2816) {  // transposes
    const int idx = (bb - 2048) & 255;
    const float* W = (bb < 2304) ? kw : (bb < 2560) ? vw : ow;
    bf16* Wt = (bb < 2304) ? (wtall + 1024 * 1024)
             : (bb < 2560) ? (wtall + 2 * 1024 * 1024) : wot;
    const int bc = (idx & 15) * 64;
    const int br = (idx >> 4) * 64;
#pragma unroll
    for (int j = 0; j < 16; j++) {
      int id2 = j * 256 + tid;
      int r = id2 >> 6, c = id2 & 63;
      t0[r][c] = W[(size_t)(br + r) * EMBED + bc + c];
    }
    __syncthreads();
#pragma unroll
    for (int j = 0; j < 16; j++) {
      int id2 = j * 256 + tid;
      int r = id2 >> 6, c = id2 & 63;
      Wt[(size_t)(bc + r) * EMBED + br + c] = (bf16)t0[c][r];
    }
    return;
  }
  if (bb < 3072) {  // weff: W_q_eff^T = (q_w @ blockdiag(E')*log2e)^T
    const int idx = bb - 2816;
    const int h = idx >> 4;
    const int ibase = (idx & 15) * 64;
#pragma unroll
    for (int j = 0; j < 16; j++) {
      int id2 = j * 256 + tid;
      int i = id2 >> 6, d = id2 & 63;
      t0[i][d] = qw[(size_t)(ibase + i) * EMBED + h * HD + d];
    }
#pragma unroll
    for (int j = 0; j < 16; j++) {
      int id2 = j * 256 + tid;
      int d = id2 >> 6, e = id2 & 63;
      float v = ent[((size_t)h * HD + d) * HD + e];
      if (d == e) { float cp = cosf(phase[h * HD + d]); v += cp * cp * 0.125f; }
      t1[d][e] = v * LOG2E;
    }
    __syncthreads();
    const int i = tid & 63;
    const int e0 = (tid >> 6) * 16;
    float s[16];
#pragma unroll
    for (int ee = 0; ee < 16; ee++) s[ee] = 0.f;
    for (int d = 0; d < 64; d++) {
      float qv = t0[i][d];
#pragma unroll
      for (int ee = 0; ee < 16; ee++) s[ee] += qv * t1[d][e0 + ee];
    }
#pragma unroll
    for (int ee = 0; ee < 16; ee++)
      wtall[(size_t)(h * HD + e0 + ee) * EMBED + ibase + i] = (bf16)s[ee];
    return;
  }
  // beff
  const int h = bb - 3072;
  if (tid < 64) {
    const int e = tid;
    float s = 0.f;
    for (int d = 0; d < 64; d++) {
      float v = ent[((size_t)h * HD + d) * HD + e];
      if (d == e) { float cp = cosf(phase[h * HD + d]); v += cp * cp * 0.125f; }
      s += qb[h * HD + d] * v;
    }
    beff[h * HD + e] = s * LOG2E;
  }
}

// ---------------- QKV GEMM (768 blocks, natural order) ----------------
// seg branch hoisted OUT of the K-loop: two specialized bodies.
// __launch_bounds__(256,4) forces VGPR<=128 -> 4 waves/SIMD -> 4 blocks/CU.
__global__ __launch_bounds__(256, 4) void gemm_qkv_kernel(
    const bf16* __restrict__ A, const bf16* __restrict__ Bt,
    const float* __restrict__ bias_q, const float* __restrict__ bias_k,
    const float* __restrict__ bias_v,
    bf16* __restrict__ Qp, bf16* __restrict__ Kp, bf16* __restrict__ Vt) {
  const int tid = threadIdx.x;
  const int lane = tid & 63, w = tid >> 6;
  const int g = lane >> 4, r15 = lane & 15;
  const int wr = w >> 1, wc = w & 1;

  const int flat = blockIdx.x;
  const int bm = (flat & 31) * 128;
  const int bn = (flat >> 5) * 128;
  const int seg = bn >> 10;

  __shared__ bf16 sA[128 * 32];
  __shared__ bf16 sB[128 * 32];

  const int srow = tid >> 2;
  const int scol = (tid & 3) << 3;
  const bf16* aptr = A + (size_t)(bm + srow) * EMBED + scol;
  const bf16* bptr = Bt + (size_t)(bn + srow) * EMBED + scol;
  bf16* la = sA + tid * 8;
  bf16* lb = sB + tid * 8;

  if (seg == 2) {
    // ---- V body: unswapped mfma(af,bfv); transposed [b,h,d][s] store ----
    f32x4 acc[4][4];
#pragma unroll
    for (int m = 0; m < 4; m++)
#pragma unroll
      for (int n = 0; n < 4; n++) acc[m][n] = (f32x4){0.f, 0.f, 0.f, 0.f};

    for (int k0 = 0; k0 < EMBED; k0 += 32) {
      __syncthreads();
      gld_lds16(aptr + k0, la);
      gld_lds16(aptr + k0 + 64 * EMBED, la + 64 * 32);
      gld_lds16(bptr + k0, lb);
      gld_lds16(bptr + k0 + 64 * EMBED, lb + 64 * 32);
      __syncthreads();
      bf16x8 af[4], bfv[4];
#pragma unroll
      for (int m = 0; m < 4; m++)
        af[m] = *(const bf16x8*)&sA[(wr * 64 + m * 16 + r15) * 32 + g * 8];
#pragma unroll
      for (int n = 0; n < 4; n++)
        bfv[n] = *(const bf16x8*)&sB[(wc * 64 + n * 16 + r15) * 32 + g * 8];
#pragma unroll
      for (int m = 0; m < 4; m++)
#pragma unroll
        for (int n = 0; n < 4; n++) acc[m][n] = mfma16(af[m], bfv[n], acc[m][n]);
    }

    const int clb = (bn & 1023) + wc * 64;
    const int orow0 = bm + wr * 64;
#pragma unroll
    for (int n = 0; n < 4; n++) {
      const int cl = clb + n * 16 + r15;
      const float bias = bias_v[cl];
      const int hh = cl >> 6, d = cl & 63;
#pragma unroll
      for (int m = 0; m < 4; m++) {
        const int row0 = orow0 + m * 16 + g * 4;
        const int b = row0 >> 11, s = row0 & 2047;
        bf16x4 pk;
#pragma unroll
        for (int r = 0; r < 4; r++) pk[r] = (bf16)(acc[m][n][r] + bias);
        *(bf16x4*)(Vt + ((size_t)((b * NH + hh) * HD + d)) * SEQ + s) = pk;
      }
    }
  } else {
    // ---- Q/K body: swapped mfma(bfv,af); bf16x4 row-major stores ----
    f32x4 acc[4][4];
#pragma unroll
    for (int m = 0; m < 4; m++)
#pragma unroll
      for (int n = 0; n < 4; n++) acc[m][n] = (f32x4){0.f, 0.f, 0.f, 0.f};

    for (int k0 = 0; k0 < EMBED; k0 += 32) {
      __syncthreads();
      gld_lds16(aptr + k0, la);
      gld_lds16(aptr + k0 + 64 * EMBED, la + 64 * 32);
      gld_lds16(bptr + k0, lb);
      gld_lds16(bptr + k0 + 64 * EMBED, lb + 64 * 32);
      __syncthreads();
      bf16x8 af[4], bfv[4];
#pragma unroll
      for (int m = 0; m < 4; m++)
        af[m] = *(const bf16x8*)&sA[(wr * 64 + m * 16 + r15) * 32 + g * 8];
#pragma unroll
      for (int n = 0; n < 4; n++)
        bfv[n] = *(const bf16x8*)&sB[(wc * 64 + n * 16 + r15) * 32 + g * 8];
#pragma unroll
      for (int m = 0; m < 4; m++)
#pragma unroll
        for (int n = 0; n < 4; n++) acc[m][n] = mfma16(bfv[n], af[m], acc[m][n]);
    }

    const float* bias = seg ? bias_k : bias_q;
    bf16* dst = seg ? Kp : Qp;
    const int clb = (bn & 1023) + wc * 64;
#pragma unroll
    for (int n = 0; n < 4; n++) {
      const int cl4 = clb + n * 16 + g * 4;
      const f32x4 b4 = *(const f32x4*)&bias[cl4];
#pragma unroll
      for (int m = 0; m < 4; m++) {
        const int tr = bm + wr * 64 + m * 16 + r15;
        bf16x4 pk;
#pragma unroll
        for (int r = 0; r < 4; r++) pk[r] = (bf16)(acc[m][n][r] + b4[r]);
        *(bf16x4*)(dst + (size_t)tr * EMBED + cl4) = pk;
      }
    }
  }
}

// ---------------- out-proj GEMM: 64x128 tile, 512 blocks ----------------
// Wave w covers cols w*32..+31 (acc[4][2]); swapped mfma -> f32x4 stores.
__global__ __launch_bounds__(256, 4) void gemm_out_kernel(
    const bf16* __restrict__ A, const bf16* __restrict__ Bt,
    const float* __restrict__ bias_o, float* __restrict__ FO) {
  const int tid = threadIdx.x;
  const int lane = tid & 63, w = tid >> 6;
  const int g = lane >> 4, r15 = lane & 15;

  const int flat = blockIdx.x;
  const int bm = (flat & 63) * 64;
  const int bn = (flat >> 6) * 128;

  __shared__ bf16 sA[64 * 32];
  __shared__ bf16 sB[128 * 32];

  f32x4 acc[4][2];
#pragma unroll
  for (int m = 0; m < 4; m++)
#pragma unroll
    for (int n = 0; n < 2; n++) acc[m][n] = (f32x4){0.f, 0.f, 0.f, 0.f};

  const int srow = tid >> 2;
  const int scol = (tid & 3) << 3;
  const bf16* aptr = A + (size_t)(bm + srow) * EMBED + scol;  // srow 0..63
  const bf16* bptr = Bt + (size_t)(bn + srow) * EMBED + scol;
  bf16* la = sA + tid * 8;
  bf16* lb = sB + tid * 8;

  for (int k0 = 0; k0 < EMBED; k0 += 32) {
    __syncthreads();
    gld_lds16(aptr + k0, la);
    gld_lds16(bptr + k0, lb);
    gld_lds16(bptr + k0 + 64 * EMBED, lb + 64 * 32);
    __syncthreads();
    bf16x8 af[4], bfv[2];
#pragma unroll
    for (int m = 0; m < 4; m++)
      af[m] = *(const bf16x8*)&sA[(m * 16 + r15) * 32 + g * 8];
#pragma unroll
    for (int n = 0; n < 2; n++)
      bfv[n] = *(const bf16x8*)&sB[(w * 32 + n * 16 + r15) * 32 + g * 8];
#pragma unroll
    for (int m = 0; m < 4; m++)
#pragma unroll
      for (int n = 0; n < 2; n++) acc[m][n] = mfma16(bfv[n], af[m], acc[m][n]);
  }

#pragma unroll
  for (int n = 0; n < 2; n++) {
    const int cl4 = bn + w * 32 + n * 16 + g * 4;
    const f32x4 b4 = *(const f32x4*)&bias_o[cl4];
#pragma unroll
    for (int m = 0; m < 4; m++) {
      const int tr = bm + m * 16 + r15;
      *(f32x4*)(FO + (size_t)tr * EMBED + cl4) = acc[m][n] + b4;
    }
  }
}

// ---------------- flash attention (32x32 MFMA, in-block KV-split) --------
// 512 blocks (XCD-swizzled) x 512 thr = 8 waves. Waves 0-3: kv [0,1024),
// waves 4-7: kv [1024,2048); each wave owns 32 q-rows with its own (m,l,O).
// Per half: KVBLK=64 K/V double-buffered LDS (XOR-swizzled), counted
// vmcnt(4). In-register P via permlane32_swap. Merge halves through LDS.
__global__ __launch_bounds__(512, 4) void flash_attn_kernel(
    const bf16* __restrict__ Qp, const bf16* __restrict__ Kp,
    const bf16* __restrict__ Vt, bf16* __restrict__ Op) {
  const int tid = threadIdx.x, lane = tid & 63, w = tid >> 6;
  const int q31 = lane & 31, hi = lane >> 5;
  const int half = w >> 2, wq = w & 3;
  // bijective XCD swizzle: 512 blocks = 8 xcd * 64; chunk = 4 bh * 16 qt
  const int flat = blockIdx.x;
  const int c = (flat & 7) * 64 + (flat >> 3);
  const int bh = c >> 4, qt = c & 15;
  const int b = bh >> 4, h = bh & 15;

  __shared__ char smem[65536];
  bf16* sKb = (bf16*)smem;             // [half*2+buf][4096] : 64 kv x 64 d
  bf16* sVb = (bf16*)(smem + 32768);   // [half*2+buf][4096] : 64 d  x 64 s

  const int g256 = tid & 255;          // within-half staging id
  const int strow = g256 >> 3;         // 0..31
  const int stcb = (g256 & 7) << 4;

  const char* kgbase = (const char*)(Kp + ((size_t)b * SEQ) * EMBED + h * HD);
  const char* vgbase = (const char*)(Vt + (size_t)bh * HD * SEQ);

  auto stage = [&](int buf, int kv0) {
    bf16* kd = sKb + (size_t)(half * 2 + buf) * 4096 + g256 * 8;
    bf16* vd = sVb + (size_t)(half * 2 + buf) * 4096 + g256 * 8;
#pragma unroll
    for (int i = 0; i < 2; i++) {
      const int row = i * 32 + strow;
      const int sb = stcb ^ ((row & 7) << 4);
      gld_lds16((const bf16*)(kgbase + (size_t)(kv0 + row) * (EMBED * 2) + sb),
                kd + i * 2048);
      gld_lds16((const bf16*)(vgbase + (size_t)row * (SEQ * 2) + (size_t)kv0 * 2 + sb),
                vd + i * 2048);
    }
  };

  const int kvbase = half * 1024;
  stage(0, kvbase);

  // Q B-operand frags: lane q31 = q-col, k-slice hi*8 within each 16-depth
  const int qbase = qt * 128 + wq * 32;
  const int qrow = qbase + q31;
  const bf16* qptr = Qp + ((size_t)(b * SEQ + qrow)) * EMBED + h * HD;
  bf16x8 aq[4];
#pragma unroll
  for (int ds = 0; ds < 4; ds++)
    aq[ds] = *(const bf16x8*)(qptr + ds * 16 + hi * 8);

  const int sz = (q31 & 7) << 4;
  int cofs[4];  // 128B-row chunk offsets: i*32 + hi*16, swizzled
#pragma unroll
  for (int i = 0; i < 4; i++) cofs[i] = ((i * 32 + hi * 16) ^ sz);

  f32x16 o0, o1;
#pragma unroll
  for (int i = 0; i < 16; i++) { o0[i] = 0.f; o1[i] = 0.f; }
  float mrow = -3.0e38f, lrow = 0.f;

  union B4 { bf16x4 v; unsigned int u[2]; };

  for (int it = 0; it < 16; ++it) {
    const int cur = it & 1;
    if (it + 1 < 16) {
      stage(cur ^ 1, kvbase + (it + 1) * 64);
      asm volatile("s_waitcnt vmcnt(4)" ::: "memory");
    } else {
      asm volatile("s_waitcnt vmcnt(0)" ::: "memory");
    }
    __builtin_amdgcn_s_barrier();

    const char* kc = (const char*)(sKb + (size_t)(half * 2 + cur) * 4096) + q31 * 128;
    const char* vc = (const char*)(sVb + (size_t)(half * 2 + cur) * 4096) + q31 * 128;

    // ---- QK^T: A = K (rows kv), B = Q -> S[kv][q] ----
    f32x16 s0, s1;
#pragma unroll
    for (int i = 0; i < 16; i++) { s0[i] = 0.f; s1[i] = 0.f; }
    __builtin_amdgcn_s_setprio(1);
#pragma unroll
    for (int ds = 0; ds < 4; ds++) {
      bf16x8 bk0 = *(const bf16x8*)(kc + cofs[ds]);
      bf16x8 bk1 = *(const bf16x8*)(kc + 4096 + cofs[ds]);
      s0 = mfma32(bk0, aq[ds], s0);
      s1 = mfma32(bk1, aq[ds], s1);
    }
    __builtin_amdgcn_s_setprio(0);

    // ---- per-lane softmax over the 32 held scores (exp2 domain) ----
    float mt = s0[0];
#pragma unroll
    for (int i = 1; i < 16; i++) mt = fmaxf(mt, s0[i]);
#pragma unroll
    for (int i = 0; i < 16; i++) mt = fmaxf(mt, s1[i]);
    {
      u32x2 sm = __builtin_amdgcn_permlane32_swap(__float_as_uint(mt),
                                                  __float_as_uint(mt), false, false);
      mt = fmaxf(__uint_as_float(sm.x), __uint_as_float(sm.y));
    }
    if (__any(mt > mrow + 8.f)) {
      const float mn = fmaxf(mrow, mt);
      const float al = fast_exp2(mrow - mn);
      mrow = mn;
      lrow *= al;
      o0 *= al;
      o1 *= al;
    }

    // P = exp2(S - mrow): pack into 8 quads (bf16x4 = 2 dwords each)
    B4 qd[8];
    float lsum = 0.f;
#pragma unroll
    for (int j = 0; j < 4; j++)
#pragma unroll
      for (int r = 0; r < 4; r++) {
        float pv = fast_exp2(s0[4 * j + r] - mrow);
        lsum += pv;
        qd[j].v[r] = (bf16)pv;
      }
#pragma unroll
    for (int j = 0; j < 4; j++)
#pragma unroll
      for (int r = 0; r < 4; r++) {
        float pv = fast_exp2(s1[4 * j + r] - mrow);
        lsum += pv;
        qd[4 + j].v[r] = (bf16)pv;
      }
    {
      u32x2 ss = __builtin_amdgcn_permlane32_swap(__float_as_uint(lsum),
                                                  __float_as_uint(lsum), false, false);
      lrow += __uint_as_float(ss.x) + __uint_as_float(ss.y);  // own + partner
    }

    // assemble PV B-fragments: frag[kt] covers kv = kt*16 .. +15
    bf16x8 pfrag[4];
#pragma unroll
    for (int kt = 0; kt < 4; kt++) {
      u32x2 p0 = __builtin_amdgcn_permlane32_swap(qd[2 * kt].u[0],
                                                  qd[2 * kt + 1].u[0], false, false);
      u32x2 p1 = __builtin_amdgcn_permlane32_swap(qd[2 * kt].u[1],
                                                  qd[2 * kt + 1].u[1], false, false);
      union { unsigned int u[4]; bf16x8 v; } f;
      f.u[0] = p0.x; f.u[1] = p1.x; f.u[2] = p0.y; f.u[3] = p1.y;
      pfrag[kt] = f.v;
    }

    // ---- PV: A = V^T (rows d), B = P -> O[d][q] ----
    __builtin_amdgcn_s_setprio(1);
#pragma unroll
    for (int kt = 0; kt < 4; kt++) {
      bf16x8 av0 = *(const bf16x8*)(vc + cofs[kt]);
      bf16x8 av1 = *(const bf16x8*)(vc + 4096 + cofs[kt]);
      o0 = mfma32(av0, pfrag[kt], o0);
      o1 = mfma32(av1, pfrag[kt], o1);
    }
    __builtin_amdgcn_s_setprio(0);
    __builtin_amdgcn_s_barrier();
  }

  // ---- merge halves through reused LDS ----
  float* shO = (float*)smem;             // [4][64][33]
  float* shML = (float*)(smem + 33792);  // [4][64][2]
  if (half == 1) {
    float* o = shO + (size_t)(wq * 64 + lane) * 33;
#pragma unroll
    for (int i = 0; i < 16; i++) { o[i] = o0[i]; o[16 + i] = o1[i]; }
    shML[(wq * 64 + lane) * 2] = mrow;
    shML[(wq * 64 + lane) * 2 + 1] = lrow;
  }
  __syncthreads();
  if (half == 0) {
    const float* o = shO + (size_t)(wq * 64 + lane) * 33;
    const float mB = shML[(wq * 64 + lane) * 2];
    const float lB = shML[(wq * 64 + lane) * 2 + 1];
    const float M = fmaxf(mrow, mB);
    const float wA = fast_exp2(mrow - M), wB = fast_exp2(mB - M);
    const float inv = 1.f / (lrow * wA + lB * wB);
    const float fA = wA * inv, fB = wB * inv;

    // O[d][q]: lane q31 owns q-col; d = 8*j + 4*hi + r (o0), +32 (o1)
    bf16* obase = Op + ((size_t)(b * SEQ + qrow)) * EMBED + h * HD;
#pragma unroll
    for (int j = 0; j < 4; j++) {
      bf16x4 st;
#pragma unroll
      for (int r = 0; r < 4; r++)
        st[r] = (bf16)(o0[4 * j + r] * fA + o[4 * j + r] * fB);
      *(bf16x4*)(obase + 8 * j + 4 * hi) = st;
    }
#pragma unroll
    for (int j = 0; j < 4; j++) {
      bf16x4 st;
#pragma unroll
      for (int r = 0; r < 4; r++)
        st[r] = (bf16)(o1[4 * j + r] * fA + o[16 + 4 * j + r] * fB);
      *(bf16x4*)(obase + 32 + 8 * j + 4 * hi) = st;
    }
  }
}

// ---------------- launch ----------------
extern "C" void kernel_launch(void* const* d_in, const int* in_sizes, int n_in,
                              void* d_out, int out_size, void* d_ws, size_t ws_size,
                              hipStream_t stream) {
  const float* x     = (const float*)d_in[0];
  const float* q_w   = (const float*)d_in[1];
  const float* q_b   = (const float*)d_in[2];
  const float* k_w   = (const float*)d_in[3];
  const float* k_b   = (const float*)d_in[4];
  const float* v_w   = (const float*)d_in[5];
  const float* v_b   = (const float*)d_in[6];
  const float* phase = (const float*)d_in[7];
  const float* ent   = (const float*)d_in[8];
  const float* out_w = (const float*)d_in[9];
  const float* out_b = (const float*)d_in[10];
  float* out = (float*)d_out;

  char* ws = (char*)d_ws;
  bf16* xb    = (bf16*)(ws + 0);          // 8388608 B, [B,S,E] bf16; reused as attn out
  bf16* wtall = (bf16*)(ws + 8388608);    // 6291456 B, [3072][1024] bf16 (Qeff|K|V)
  bf16* wot   = (bf16*)(ws + 14680064);   // 2097152 B, out_w^T bf16
  float* beff = (float*)(ws + 16777216);  // 4096 B
  bf16* Qp    = (bf16*)(ws + 16781312);   // 8388608 B
  bf16* Kp    = (bf16*)(ws + 25169920);   // 8388608 B
  bf16* Vt    = (bf16*)(ws + 33558528);   // 8388608 B, [b,h,d,s]
  (void)in_sizes; (void)n_in; (void)out_size; (void)ws_size;

  prep_kernel<<<3088, 256, 0, stream>>>(x, q_w, q_b, k_w, v_w, out_w, ent, phase,
                                        xb, wtall, wot, beff);

  gemm_qkv_kernel<<<768, 256, 0, stream>>>(
      xb, wtall, beff, k_b, v_b, Qp, Kp, Vt);

  flash_attn_kernel<<<512, 512, 0, stream>>>(Qp, Kp, Vt, xb);

  gemm_out_kernel<<<512, 256, 0, stream>>>(xb, wot, out_b, out);
}